// Round 1
// baseline (162.116 us; speedup 1.0000x reference)
//
#include <hip/hip_runtime.h>
#include <hip/hip_bf16.h>
#include <math.h>

typedef __bf16 bf16x8 __attribute__((ext_vector_type(8)));
typedef float f32x4 __attribute__((ext_vector_type(4)));
typedef unsigned short ushortx8 __attribute__((ext_vector_type(8)));
typedef unsigned short ushortx4 __attribute__((ext_vector_type(4)));

#define N_TOTAL 262144
#define D 128
#define K_TOTAL 1024
#define BN 128
#define NBLK (N_TOTAL / BN)  // 2048

__device__ __forceinline__ unsigned short f2bf(float x) {
  union { float f; unsigned u; } c;
  c.f = x;
  unsigned u = c.u;
  u += 0x7fffu + ((u >> 16) & 1u);  // RNE
  return (unsigned short)(u >> 16);
}

// Kernel 1: means fp32 -> bf16, plus 0.5*||m||^2 per centroid.
__global__ void prep_means(const float* __restrict__ means,
                           unsigned short* __restrict__ mbf,
                           float* __restrict__ m2h) {
  int k = blockIdx.x, t = threadIdx.x;  // 1024 blocks x 64 threads
  float a = means[k * D + t];
  float b = means[k * D + t + 64];
  mbf[k * D + t] = f2bf(a);
  mbf[k * D + t + 64] = f2bf(b);
  float s = a * a + b * b;
#pragma unroll
  for (int m = 32; m; m >>= 1) s += __shfl_down(s, m, 64);
  if (t == 0) m2h[k] = 0.5f * s;
}

// Kernel 2: per-block 128 rows: bf16-MFMA argmax of (x.m - 0.5*||m||^2)
// over all 1024 centroids, then exact fp32 loss for the winners.
__global__ __launch_bounds__(256) void kmeans_main(
    const float* __restrict__ X, const unsigned short* __restrict__ mbf,
    const float* __restrict__ m2h, const float* __restrict__ means,
    float* __restrict__ partials) {
  __shared__ __attribute__((aligned(16))) char Xs[BN * 256];  // 32 KB bf16 swizzled
  __shared__ __attribute__((aligned(16))) char Bs[64 * 256];  // 16 KB bf16 swizzled
  __shared__ float m2s[K_TOTAL];                              // 4 KB
  __shared__ int idxs[BN];
  __shared__ float wsum[4];

  const int t = threadIdx.x;
  const int l = t & 63;
  const int w = t >> 6;
  const int lr = l & 15;
  const int lhi = l >> 4;
  const long nbase = (long)blockIdx.x * BN;

  // ---- stage X tile: 128x128 fp32 -> bf16 into swizzled LDS ----
  const float4* Xg = (const float4*)(X + nbase * D);
#pragma unroll
  for (int j = 0; j < 16; ++j) {
    float4 v = Xg[j * 256 + t];
    int f = (j * 256 + t) * 4;  // float index in tile
    int row = f >> 7;
    int colb = (f & 127) * 2;  // byte col
    unsigned off = (unsigned)(row * 256 + colb) ^ (unsigned)((row & 7) << 4);
    ushortx4 p;
    p[0] = f2bf(v.x); p[1] = f2bf(v.y); p[2] = f2bf(v.z); p[3] = f2bf(v.w);
    *(ushortx4*)(Xs + off) = p;
  }
  // ---- stage m2h into LDS ----
  {
    float4 v = ((const float4*)m2h)[t];  // 256*4 = 1024
    *(float4*)(m2s + t * 4) = v;
  }

  // ---- precompute swizzled fragment offsets (k-step invariant) ----
  unsigned aoff[2][4], boff[4][4];
#pragma unroll
  for (int rs = 0; rs < 2; ++rs)
#pragma unroll
    for (int ds = 0; ds < 4; ++ds) {
      int row = w * 32 + rs * 16 + lr;
      aoff[rs][ds] =
          (unsigned)(row * 256 + ds * 64 + lhi * 16) ^ (unsigned)((row & 7) << 4);
    }
#pragma unroll
  for (int kt = 0; kt < 4; ++kt)
#pragma unroll
    for (int ds = 0; ds < 4; ++ds) {
      int brow = kt * 16 + lr;
      boff[kt][ds] =
          (unsigned)(brow * 256 + ds * 64 + lhi * 16) ^ (unsigned)((brow & 7) << 4);
    }

  float bv[2][4];
  int bi[2][4];
#pragma unroll
  for (int rs = 0; rs < 2; ++rs)
#pragma unroll
    for (int r = 0; r < 4; ++r) {
      bv[rs][r] = -3.402823466e38f;
      bi[rs][r] = 0;
    }

  __syncthreads();

  for (int ks = 0; ks < 16; ++ks) {
    // ---- stage B tile: 64 centroids x 128 d (bf16) ----
    const ushortx8* Bg = (const ushortx8*)(mbf + ks * 64 * D);
#pragma unroll
    for (int j = 0; j < 4; ++j) {
      int c = j * 256 + t;
      ushortx8 v = Bg[c];
      unsigned fb = (unsigned)c * 16;
      unsigned off = fb ^ (((fb >> 8) & 7u) << 4);
      *(ushortx8*)(Bs + off) = v;
    }
    __syncthreads();

    f32x4 acc[2][4];
#pragma unroll
    for (int rs = 0; rs < 2; ++rs)
#pragma unroll
      for (int kt = 0; kt < 4; ++kt)
#pragma unroll
        for (int e = 0; e < 4; ++e) acc[rs][kt][e] = 0.f;

#pragma unroll
    for (int ds = 0; ds < 4; ++ds) {
      bf16x8 a0 = *(const bf16x8*)(Xs + aoff[0][ds]);
      bf16x8 a1 = *(const bf16x8*)(Xs + aoff[1][ds]);
      bf16x8 b0 = *(const bf16x8*)(Bs + boff[0][ds]);
      bf16x8 b1 = *(const bf16x8*)(Bs + boff[1][ds]);
      bf16x8 b2 = *(const bf16x8*)(Bs + boff[2][ds]);
      bf16x8 b3 = *(const bf16x8*)(Bs + boff[3][ds]);
      acc[0][0] = __builtin_amdgcn_mfma_f32_16x16x32_bf16(a0, b0, acc[0][0], 0, 0, 0);
      acc[0][1] = __builtin_amdgcn_mfma_f32_16x16x32_bf16(a0, b1, acc[0][1], 0, 0, 0);
      acc[0][2] = __builtin_amdgcn_mfma_f32_16x16x32_bf16(a0, b2, acc[0][2], 0, 0, 0);
      acc[0][3] = __builtin_amdgcn_mfma_f32_16x16x32_bf16(a0, b3, acc[0][3], 0, 0, 0);
      acc[1][0] = __builtin_amdgcn_mfma_f32_16x16x32_bf16(a1, b0, acc[1][0], 0, 0, 0);
      acc[1][1] = __builtin_amdgcn_mfma_f32_16x16x32_bf16(a1, b1, acc[1][1], 0, 0, 0);
      acc[1][2] = __builtin_amdgcn_mfma_f32_16x16x32_bf16(a1, b2, acc[1][2], 0, 0, 0);
      acc[1][3] = __builtin_amdgcn_mfma_f32_16x16x32_bf16(a1, b3, acc[1][3], 0, 0, 0);
    }

    // ---- running argmax of (dot - 0.5*||m||^2) ----
    const int kbase = ks * 64;
#pragma unroll
    for (int kt = 0; kt < 4; ++kt) {
      float m2 = m2s[kbase + kt * 16 + lr];
      int kidx = kbase + kt * 16 + lr;
#pragma unroll
      for (int rs = 0; rs < 2; ++rs)
#pragma unroll
        for (int r = 0; r < 4; ++r) {
          float v = acc[rs][kt][r] - m2;
          if (v > bv[rs][r]) {
            bv[rs][r] = v;
            bi[rs][r] = kidx;
          }
        }
    }
    __syncthreads();
  }

  // ---- reduce (val,idx) across the 16 lanes holding the same row ----
#pragma unroll
  for (int rs = 0; rs < 2; ++rs)
#pragma unroll
    for (int r = 0; r < 4; ++r) {
      float v = bv[rs][r];
      int i = bi[rs][r];
#pragma unroll
      for (int m = 1; m < 16; m <<= 1) {
        float ov = __shfl_xor(v, m, 64);
        int oi = __shfl_xor(i, m, 64);
        if (ov > v || (ov == v && oi < i)) {
          v = ov;
          i = oi;
        }
      }
      if (lr == 0) idxs[w * 32 + rs * 16 + lhi * 4 + r] = i;
    }
  __syncthreads();

  // ---- exact fp32 loss for assigned centroids ----
  {
    int row = t >> 1, h = t & 1;
    long n = nbase + row;
    int a = idxs[row];
    const float4* xr = (const float4*)(X + n * D + h * 64);
    const float4* mr = (const float4*)(means + (long)a * D + h * 64);
    float s = 0.f;
#pragma unroll
    for (int i = 0; i < 16; ++i) {
      float4 xv = xr[i];
      float4 mv = mr[i];
      float d0 = xv.x - mv.x, d1 = xv.y - mv.y;
      float d2 = xv.z - mv.z, d3 = xv.w - mv.w;
      s = fmaf(d0, d0, s);
      s = fmaf(d1, d1, s);
      s = fmaf(d2, d2, s);
      s = fmaf(d3, d3, s);
    }
#pragma unroll
    for (int m = 32; m; m >>= 1) s += __shfl_down(s, m, 64);
    if (l == 0) wsum[w] = s;
  }
  __syncthreads();
  if (t == 0) partials[blockIdx.x] = wsum[0] + wsum[1] + wsum[2] + wsum[3];
}

// Kernel 3: deterministic fixed-order final reduction (double accum).
__global__ void reduce_loss(const float* __restrict__ partials,
                            float* __restrict__ out) {
  __shared__ double ws[4];
  int t = threadIdx.x;
  double s = 0.0;
  for (int i = t; i < NBLK; i += 256) s += (double)partials[i];
#pragma unroll
  for (int m = 32; m; m >>= 1) s += __shfl_down(s, m, 64);
  if ((t & 63) == 0) ws[t >> 6] = s;
  __syncthreads();
  if (t == 0) out[0] = (float)(ws[0] + ws[1] + ws[2] + ws[3]);
}

extern "C" void kernel_launch(void* const* d_in, const int* in_sizes, int n_in,
                              void* d_out, int out_size, void* d_ws,
                              size_t ws_size, hipStream_t stream) {
  const float* X = (const float*)d_in[0];
  const float* means = (const float*)d_in[1];
  float* out = (float*)d_out;
  char* ws = (char*)d_ws;
  unsigned short* mbf = (unsigned short*)ws;        // 262144 B
  float* m2h = (float*)(ws + 262144);               // 4096 B
  float* partials = (float*)(ws + 262144 + 4096);   // 8192 B

  prep_means<<<K_TOTAL, 64, 0, stream>>>(means, mbf, m2h);
  kmeans_main<<<NBLK, 256, 0, stream>>>(X, mbf, m2h, means, partials);
  reduce_loss<<<1, 256, 0, stream>>>(partials, out);
}

// Round 3
// 111.394 us; speedup vs baseline: 1.4553x; 1.4553x over previous
//
#include <hip/hip_runtime.h>
#include <hip/hip_bf16.h>

typedef __bf16 bf16x8 __attribute__((ext_vector_type(8)));
typedef float f32x4 __attribute__((ext_vector_type(4)));
typedef unsigned short ushortx8 __attribute__((ext_vector_type(8)));

#define N_TOTAL 262144
#define D 128
#define K_TOTAL 1024
#define BN 256
#define NBLK (N_TOTAL / BN)  // 1024
#define BIGF 256.0f
#define BTILE_BYTES 16384  // 64 centroids x 128 dims x 2 B

__device__ __forceinline__ unsigned short f2bf(float x) {
  union { float f; unsigned u; } c;
  c.f = x;
  unsigned u = c.u;
  u += 0x7fffu + ((u >> 16) & 1u);  // RNE
  return (unsigned short)(u >> 16);
}

// Kernel 1: means fp32 -> bf16, plus BIG - 0.5*||m||^2 per centroid.
__global__ void prep_means(const float* __restrict__ means,
                           unsigned short* __restrict__ mbf,
                           float* __restrict__ bigm2) {
  int k = blockIdx.x, t = threadIdx.x;  // 1024 blocks x 64 threads
  float a = means[k * D + t];
  float b = means[k * D + t + 64];
  mbf[k * D + t] = f2bf(a);
  mbf[k * D + t + 64] = f2bf(b);
  float s = a * a + b * b;
#pragma unroll
  for (int m = 32; m; m >>= 1) s += __shfl_down(s, m, 64);
  if (t == 0) bigm2[k] = BIGF - 0.5f * s;
}

__device__ __forceinline__ void gload_lds16(const void* g, void* l) {
  __builtin_amdgcn_global_load_lds(
      (const __attribute__((address_space(1))) unsigned int*)g,
      (__attribute__((address_space(3))) unsigned int*)l, 16, 0, 0);
}

// Kernel 2: 256 rows/block, 4 waves x 64 rows. A-fragments in registers,
// B double-buffered in swizzled LDS via global_load_lds, packed-key argmax,
// exact fp32 loss for the winners.
__global__ __launch_bounds__(256, 2) void kmeans_main(
    const float* __restrict__ X, const unsigned short* __restrict__ mbf,
    const float* __restrict__ bigm2, const float* __restrict__ means,
    float* __restrict__ partials) {
  __shared__ __attribute__((aligned(16))) char Bs[2][BTILE_BYTES];  // 32 KB dbuf
  __shared__ float m2s[K_TOTAL];                                    // 4 KB
  __shared__ int idxs[BN];
  __shared__ float wsum[4];

  const int t = threadIdx.x;
  const int l = t & 63;
  const int w = t >> 6;
  const int lr = l & 15;
  const int lhi = l >> 4;
  const long nbase = (long)blockIdx.x * BN;

  // ---- stage B tile ks=0 (pre-swizzled global source, linear LDS dest) ----
  {
    const char* src = (const char*)mbf;
#pragma unroll
    for (int j = 0; j < 4; ++j) {
      unsigned doff = (unsigned)(w * 4096 + j * 1024 + l * 16);
      unsigned soff = doff ^ (((doff >> 8) & 7u) << 4);
      gload_lds16(src + soff, Bs[0] + (w * 4096 + j * 1024));
    }
  }

  // ---- A fragments: 64 rows/wave, loaded once from global, bf16 in regs ----
  bf16x8 a[4][4];  // [row-sub][d-sub]
#pragma unroll
  for (int rs = 0; rs < 4; ++rs)
#pragma unroll
    for (int ds = 0; ds < 4; ++ds) {
      const float* ap =
          X + (nbase + w * 64 + rs * 16 + lr) * D + ds * 32 + lhi * 8;
      float4 v0 = *(const float4*)ap;
      float4 v1 = *(const float4*)(ap + 4);
      ushortx8 p;
      p[0] = f2bf(v0.x); p[1] = f2bf(v0.y); p[2] = f2bf(v0.z); p[3] = f2bf(v0.w);
      p[4] = f2bf(v1.x); p[5] = f2bf(v1.y); p[6] = f2bf(v1.z); p[7] = f2bf(v1.w);
      union { ushortx8 u; bf16x8 b; } cv;
      cv.u = p;
      a[rs][ds] = cv.b;
    }

  // ---- stage bigm2 into LDS ----
  {
    float4 v = ((const float4*)bigm2)[t];  // 256*4 = 1024
    *(float4*)(m2s + t * 4) = v;
  }

  // ---- per-lane swizzled in-row B offsets (kt goes into the imm) ----
  int roff[4];
#pragma unroll
  for (int ds = 0; ds < 4; ++ds)
    roff[ds] = lr * 256 + ((ds * 64 + lhi * 16) ^ ((lr & 7) << 4));

  unsigned bk[4][4];  // running packed keys per (rs, e)
#pragma unroll
  for (int rs = 0; rs < 4; ++rs)
#pragma unroll
    for (int e = 0; e < 4; ++e) bk[rs][e] = 0u;

  __syncthreads();

  int cur = 0;
#pragma unroll 2
  for (int ks = 0; ks < 16; ++ks) {
    // prefetch next B tile into the other buffer (completes by __syncthreads)
    if (ks < 15) {
      const char* src = (const char*)mbf + (ks + 1) * BTILE_BYTES;
      char* dstbase = Bs[cur ^ 1];
#pragma unroll
      for (int j = 0; j < 4; ++j) {
        unsigned doff = (unsigned)(w * 4096 + j * 1024 + l * 16);
        unsigned soff = doff ^ (((doff >> 8) & 7u) << 4);
        gload_lds16(src + soff, dstbase + (w * 4096 + j * 1024));
      }
    }

    const char* bp = Bs[cur];
    float bm[4];
#pragma unroll
    for (int kt = 0; kt < 4; ++kt) bm[kt] = m2s[ks * 64 + kt * 16 + lr];

    f32x4 acc[4][4];
    // ds = 0: C-init = BIG - 0.5||m||^2 (no explicit zero/sub pass)
#pragma unroll
    for (int kt = 0; kt < 4; ++kt) {
      bf16x8 b = *(const bf16x8*)(bp + kt * 4096 + roff[0]);
      f32x4 cinit = {bm[kt], bm[kt], bm[kt], bm[kt]};
#pragma unroll
      for (int rs = 0; rs < 4; ++rs)
        acc[rs][kt] =
            __builtin_amdgcn_mfma_f32_16x16x32_bf16(a[rs][0], b, cinit, 0, 0, 0);
    }
#pragma unroll
    for (int ds = 1; ds < 4; ++ds)
#pragma unroll
      for (int kt = 0; kt < 4; ++kt) {
        bf16x8 b = *(const bf16x8*)(bp + kt * 4096 + roff[ds]);
#pragma unroll
        for (int rs = 0; rs < 4; ++rs)
          acc[rs][kt] = __builtin_amdgcn_mfma_f32_16x16x32_bf16(
              a[rs][ds], b, acc[rs][kt], 0, 0, 0);
      }

    // ---- packed-key running argmax: 2 VALU ops per element ----
#pragma unroll
    for (int kt = 0; kt < 4; ++kt) {
      unsigned kidx = (unsigned)(ks * 64 + kt * 16 + lr);
#pragma unroll
      for (int rs = 0; rs < 4; ++rs)
#pragma unroll
        for (int e = 0; e < 4; ++e) {
          unsigned key = (__float_as_uint(acc[rs][kt][e]) & 0xFFFFFC00u) | kidx;
          bk[rs][e] = bk[rs][e] > key ? bk[rs][e] : key;
        }
    }

    __syncthreads();
    cur ^= 1;
  }

  // ---- reduce keys across the 16 column-lanes; extract centroid idx ----
#pragma unroll
  for (int rs = 0; rs < 4; ++rs)
#pragma unroll
    for (int e = 0; e < 4; ++e) {
      unsigned k = bk[rs][e];
#pragma unroll
      for (int m = 1; m < 16; m <<= 1) {
        unsigned o = (unsigned)__shfl_xor((int)k, m, 64);
        k = k > o ? k : o;
      }
      if (lr == 0) idxs[w * 64 + rs * 16 + lhi * 4 + e] = (int)(k & 1023u);
    }
  __syncthreads();

  // ---- exact fp32 loss for assigned centroids (1 row per thread) ----
  {
    long n = nbase + t;
    int ai = idxs[t];
    const float4* xr = (const float4*)(X + n * D);
    const float4* mr = (const float4*)(means + (long)ai * D);
    float s = 0.f;
#pragma unroll 8
    for (int i = 0; i < 32; ++i) {
      float4 xv = xr[i];
      float4 mv = mr[i];
      float d0 = xv.x - mv.x, d1 = xv.y - mv.y;
      float d2 = xv.z - mv.z, d3 = xv.w - mv.w;
      s = fmaf(d0, d0, s);
      s = fmaf(d1, d1, s);
      s = fmaf(d2, d2, s);
      s = fmaf(d3, d3, s);
    }
#pragma unroll
    for (int m = 32; m; m >>= 1) s += __shfl_down(s, m, 64);
    if (l == 0) wsum[w] = s;
  }
  __syncthreads();
  if (t == 0) partials[blockIdx.x] = wsum[0] + wsum[1] + wsum[2] + wsum[3];
}

// Kernel 3: deterministic fixed-order final reduction (double accum).
__global__ void reduce_loss(const float* __restrict__ partials,
                            float* __restrict__ out) {
  __shared__ double ws[4];
  int t = threadIdx.x;
  double s = 0.0;
  for (int i = t; i < NBLK; i += 256) s += (double)partials[i];
#pragma unroll
  for (int m = 32; m; m >>= 1) s += __shfl_down(s, m, 64);
  if ((t & 63) == 0) ws[t >> 6] = s;
  __syncthreads();
  if (t == 0) out[0] = (float)(ws[0] + ws[1] + ws[2] + ws[3]);
}

extern "C" void kernel_launch(void* const* d_in, const int* in_sizes, int n_in,
                              void* d_out, int out_size, void* d_ws,
                              size_t ws_size, hipStream_t stream) {
  const float* X = (const float*)d_in[0];
  const float* means = (const float*)d_in[1];
  float* out = (float*)d_out;
  char* ws = (char*)d_ws;
  unsigned short* mbf = (unsigned short*)ws;        // 262144 B
  float* bigm2 = (float*)(ws + 262144);             // 4096 B
  float* partials = (float*)(ws + 262144 + 4096);   // 4096 B

  prep_means<<<K_TOTAL, 64, 0, stream>>>(means, mbf, bigm2);
  kmeans_main<<<NBLK, 256, 0, stream>>>(X, mbf, bigm2, means, partials);
  reduce_loss<<<1, 256, 0, stream>>>(partials, out);
}